// Round 4
// baseline (216.108 us; speedup 1.0000x reference)
//
#include <hip/hip_runtime.h>
#include <math.h>

// KabschLoss: loss = mean( (xc @ R - yc)^2 ), R = U Vh from SVD of C = xc^T yc.
// Identity: sum |xc R - yc|^2 = Sx + Sy - 2*nuclear_norm(C). Only per-batch raw
// moments + singular values of the 3x3 covariance needed (closed-form eig; exact
// vs harness in R0-R2, absmax 0.0).
//
// R3: R2's block-serial stage->syncthreads->compute structure left the memory
// pipe idle between rounds (80 us at 2.5 TB/s effective; latency-bound).
// Fix: per-wave independent tiles (no __syncthreads in loop), double-buffered
// LDS, explicit per-wave vmcnt(0), prefetch of tile t+1 issued right after the
// ds_reads of tile t so DMA flies during ~1000 cy of compute. global_load_lds
// has no VGPR dests -> outstanding loads are free of register pressure.
// 512 blocks x 4 waves = 2048 waves x 16 tiles (2 batches each), 2 blocks/CU.

#define NPTS 128
#define WPB 4                    // waves per block
#define BLOCKS 512
#define TOTAL_WAVES (BLOCKS * WPB)   // 2048
#define TILE_F4 192              // float4 per array per 2-batch tile
#define BUF_F4 (2 * TILE_F4)     // x tile + y tile = 6 KB

__device__ __forceinline__ float xsum(float v, int m) {
    return v + __shfl_xor(v, m);
}

__device__ __forceinline__ void stage_tile(const float4* __restrict__ x4,
                                           const float4* __restrict__ y4,
                                           size_t tile, float4* buf, int lane) {
    const size_t base = tile * TILE_F4;
    #pragma unroll
    for (int r = 0; r < 3; ++r) {
        __builtin_amdgcn_global_load_lds(
            (const __attribute__((address_space(1))) void*)(x4 + base + r * 64 + lane),
            (__attribute__((address_space(3))) void*)(buf + r * 64), 16, 0, 0);
        __builtin_amdgcn_global_load_lds(
            (const __attribute__((address_space(1))) void*)(y4 + base + r * 64 + lane),
            (__attribute__((address_space(3))) void*)(buf + TILE_F4 + r * 64), 16, 0, 0);
    }
}

__global__ __launch_bounds__(256, 2) void kabsch_kernel(
        const float4* __restrict__ x4, const float4* __restrict__ y4,
        float* __restrict__ out, float scale, int tilesPerWave) {
    __shared__ float4 smem[WPB][2][BUF_F4];   // 48 KB
    __shared__ float wsum[WPB];

    const int tid  = threadIdx.x;
    const int lane = tid & 63;
    const int wave = tid >> 6;
    const int w    = blockIdx.x * WPB + wave;     // global wave id

    float4* buf0 = &smem[wave][0][0];
    float4* buf1 = &smem[wave][1][0];

    // Prologue: loads for tile 0.
    stage_tile(x4, y4, (size_t)w, buf0, lane);

    const int g   = lane >> 5;    // batch within tile (32 lanes per batch)
    const int sub = lane & 31;    // 4 points per lane
    const float invN = 1.0f / (float)NPTS;

    float wave_acc = 0.f;

    for (int t = 0; t < tilesPerWave; ++t) {
        float4* cur = (t & 1) ? buf1 : buf0;
        float4* nxt = (t & 1) ? buf0 : buf1;

        // Drain this wave's 6 outstanding DMA loads (per-wave, no barrier).
        asm volatile("s_waitcnt vmcnt(0)" ::: "memory");

        const float4* xs = cur + g * 96 + sub * 3;
        const float4* ys = cur + TILE_F4 + g * 96 + sub * 3;
        float4 xv0 = xs[0], xv1 = xs[1], xv2 = xs[2];
        float4 yv0 = ys[0], yv1 = ys[1], yv2 = ys[2];

        // Prefetch tile t+1 while we compute tile t.
        if (t + 1 < tilesPerWave)
            stage_tile(x4, y4, (size_t)w + (size_t)(t + 1) * TOTAL_WAVES, nxt, lane);

        float fx[12], fy[12];
        fx[0]=xv0.x; fx[1]=xv0.y; fx[2]=xv0.z; fx[3]=xv0.w;
        fx[4]=xv1.x; fx[5]=xv1.y; fx[6]=xv1.z; fx[7]=xv1.w;
        fx[8]=xv2.x; fx[9]=xv2.y; fx[10]=xv2.z; fx[11]=xv2.w;
        fy[0]=yv0.x; fy[1]=yv0.y; fy[2]=yv0.z; fy[3]=yv0.w;
        fy[4]=yv1.x; fy[5]=yv1.y; fy[6]=yv1.z; fy[7]=yv1.w;
        fy[8]=yv2.x; fy[9]=yv2.y; fy[10]=yv2.z; fy[11]=yv2.w;

        float sx0=0.f,sx1=0.f,sx2=0.f, sy0=0.f,sy1=0.f,sy2=0.f;
        float qx=0.f, qy=0.f;
        float c00=0.f,c01=0.f,c02=0.f,c10=0.f,c11=0.f,c12=0.f,
              c20=0.f,c21=0.f,c22=0.f;

        #pragma unroll
        for (int p = 0; p < 4; ++p) {
            float px0=fx[3*p], px1=fx[3*p+1], px2=fx[3*p+2];
            float py0=fy[3*p], py1=fy[3*p+1], py2=fy[3*p+2];
            sx0+=px0; sx1+=px1; sx2+=px2;
            sy0+=py0; sy1+=py1; sy2+=py2;
            qx = fmaf(px0,px0,fmaf(px1,px1,fmaf(px2,px2,qx)));
            qy = fmaf(py0,py0,fmaf(py1,py1,fmaf(py2,py2,qy)));
            c00=fmaf(px0,py0,c00); c01=fmaf(px0,py1,c01); c02=fmaf(px0,py2,c02);
            c10=fmaf(px1,py0,c10); c11=fmaf(px1,py1,c11); c12=fmaf(px1,py2,c12);
            c20=fmaf(px2,py0,c20); c21=fmaf(px2,py1,c21); c22=fmaf(px2,py2,c22);
        }

        // Butterfly reduce the 17 sums within each 32-lane group.
        #pragma unroll
        for (int m = 1; m <= 16; m <<= 1) {
            sx0=xsum(sx0,m); sx1=xsum(sx1,m); sx2=xsum(sx2,m);
            sy0=xsum(sy0,m); sy1=xsum(sy1,m); sy2=xsum(sy2,m);
            qx =xsum(qx ,m); qy =xsum(qy ,m);
            c00=xsum(c00,m); c01=xsum(c01,m); c02=xsum(c02,m);
            c10=xsum(c10,m); c11=xsum(c11,m); c12=xsum(c12,m);
            c20=xsum(c20,m); c21=xsum(c21,m); c22=xsum(c22,m);
        }

        // Mean-centered covariance and deviations.
        float C00 = c00 - sx0*sy0*invN, C01 = c01 - sx0*sy1*invN, C02 = c02 - sx0*sy2*invN;
        float C10 = c10 - sx1*sy0*invN, C11 = c11 - sx1*sy1*invN, C12 = c12 - sx1*sy2*invN;
        float C20 = c20 - sx2*sy0*invN, C21 = c21 - sx2*sy1*invN, C22 = c22 - sx2*sy2*invN;
        float Sx = qx - (sx0*sx0 + sx1*sx1 + sx2*sx2) * invN;
        float Sy = qy - (sy0*sy0 + sy1*sy1 + sy2*sy2) * invN;

        // A = C^T C; closed-form eigenvalues -> nuclear norm of C.
        float a00 = C00*C00 + C10*C10 + C20*C20;
        float a01 = C00*C01 + C10*C11 + C20*C21;
        float a02 = C00*C02 + C10*C12 + C20*C22;
        float a11 = C01*C01 + C11*C11 + C21*C21;
        float a12 = C01*C02 + C11*C12 + C21*C22;
        float a22 = C02*C02 + C12*C12 + C22*C22;

        float q = (a00 + a11 + a22) * (1.0f / 3.0f);
        float b00 = a00 - q, b11 = a11 - q, b22 = a22 - q;
        float p2 = (b00*b00 + b11*b11 + b22*b22
                    + 2.0f * (a01*a01 + a02*a02 + a12*a12)) * (1.0f / 6.0f);
        float p = sqrtf(fmaxf(p2, 0.0f));
        float detB = b00 * (b11*b22 - a12*a12)
                   - a01 * (a01*b22 - a12*a02)
                   + a02 * (a01*a12 - b11*a02);
        float p3 = p * p * p;
        float r = (p3 > 1e-30f) ? (0.5f * detB / p3) : 0.0f;
        r = fminf(1.0f, fmaxf(-1.0f, r));
        float phi = acosf(r) * (1.0f / 3.0f);
        float two_p = 2.0f * p;
        float l1 = q + two_p * cosf(phi);
        float l3 = q + two_p * cosf(phi + 2.0943951023931953f);
        float l2 = 3.0f * q - l1 - l3;
        float nuc = sqrtf(fmaxf(l1, 0.0f)) + sqrtf(fmaxf(l2, 0.0f))
                  + sqrtf(fmaxf(l3, 0.0f));

        float term = Sx + Sy - 2.0f * nuc;
        term += __shfl_xor(term, 32);   // combine the wave's two batches
        wave_acc += term;
    }

    if (lane == 0) wsum[wave] = wave_acc;
    __syncthreads();
    if (tid == 0) {
        float tsum = (wsum[0] + wsum[1] + wsum[2] + wsum[3]) * scale;
        atomicAdd(out, tsum);
    }
}

extern "C" void kernel_launch(void* const* d_in, const int* in_sizes, int n_in,
                              void* d_out, int out_size, void* d_ws, size_t ws_size,
                              hipStream_t stream) {
    const float4* x4 = (const float4*)d_in[0];
    const float4* y4 = (const float4*)d_in[1];
    float* out = (float*)d_out;

    const int B = in_sizes[0] / (NPTS * 3);         // 65536
    const int totalTiles = B / 2;                   // 32768 two-batch tiles
    const int tilesPerWave = totalTiles / TOTAL_WAVES;  // 16
    const float scale = 1.0f / ((float)B * (float)NPTS * 3.0f);

    hipMemsetAsync(out, 0, sizeof(float), stream);  // harness poisons d_out
    kabsch_kernel<<<BLOCKS, WPB * 64, 0, stream>>>(x4, y4, out, scale, tilesPerWave);
}